// Round 7
// baseline (142.391 us; speedup 1.0000x reference)
//
#include <hip/hip_runtime.h>

#define NN 50000
#define NC 256
#define DD 64
#define HH 128
#define EVV 800000
#define EVC 400000
#define NE 1200000
#define NB 196              // coarse buckets of 256 vertices (d>>8)
#define BCAP 8192           // records per bucket region; mean 6122, +26 sigma
#define MLPV_B 782          // ceil(NN/64)  (64 rows/block, 16/wave via MFMA)
#define MLPC_B 4            // NC/64
#define MLP_B (MLPV_B + MLPC_B)   // 786
#define FILL_EPB 8192       // edges per fill block (1024 thr x 8)
#define FILL_B 147          // ceil(NE/8192)
#define GAT_B (NB * 2)      // 392: two half-bucket blocks per bucket
#define VCAP 64             // slots per vertex; Poisson(24), P(>64) ~ 1e-11
#define ZROW (NN + NC)      // zeros table row used for list padding (50256)
#define HROW 136            // H-tile row pitch (128 + 8 pad: kills bank conflicts)

typedef __attribute__((ext_vector_type(8))) short bf16x8;
typedef __attribute__((ext_vector_type(4))) float f32x4;

__device__ __forceinline__ unsigned short f2bf(float x) {
  unsigned u = __float_as_uint(x);
  u = (u + 0x7fffu + ((u >> 16) & 1u)) >> 16;  // round-to-nearest-even
  return (unsigned short)u;
}

// ---------------------------------------------------------------------------
// Weight prep + gcur zero + table zero-row (used to pad gather lists).
// wt layout: W1t_v [128][64] | W2t_v [64][128] | W1t_c | W2t_c  (8192 each)
// W1t[n][k] = bf16(W1[k][n]); W2t[n][k] = bf16(W2[k][n]).
// ---------------------------------------------------------------------------
__global__ __launch_bounds__(256) void prep_kernel(
    const float* __restrict__ W1v, const float* __restrict__ W2v,
    const float* __restrict__ W1c, const float* __restrict__ W2c,
    unsigned short* __restrict__ wt, int* __restrict__ gcur,
    unsigned short* __restrict__ table) {
  const int tid = blockIdx.x * 256 + threadIdx.x;  // 0..32767
  if (tid < NB) gcur[tid] = 0;
  if (tid < DD) table[(size_t)ZROW * DD + tid] = 0;  // zeros row for padding
  const int sel = tid >> 13;
  const int t = tid & 8191;
  unsigned short* dst = wt + sel * 8192;
  if (sel == 0) {
    const int n = t >> 6, k = t & 63;
    dst[t] = f2bf(W1v[k * HH + n]);
  } else if (sel == 1) {
    const int n = t >> 7, k = t & 127;
    dst[t] = f2bf(W2v[k * DD + n]);
  } else if (sel == 2) {
    const int n = t >> 6, k = t & 63;
    dst[t] = f2bf(W1c[k * HH + n]);
  } else {
    const int n = t >> 7, k = t & 127;
    dst[t] = f2bf(W2c[k * DD + n]);
  }
}

// ---------------------------------------------------------------------------
// MFMA MLP, 16 rows per wave (4 waves -> 64 rows/block):
//   H[16x128] = relu(X[16x64] @ W1 + b1)   -- 8 ntiles x 2 mfma_16x16x32_bf16
//   O[16x64]  = H @ W2 + b2                -- 4 ntiles x 4 mfma
// Fragment layouts (verified m89/m120): A[m=lane&15][k=quad*8+j],
// B[k=quad*8+j][n=lane&15], C/D col=lane&15 row=quad*4+reg.
// H transposes C->A layout through a wave-private padded LDS tile (no
// barrier: in-wave lgkmcnt ordering suffices -- validated r14).
// ---------------------------------------------------------------------------
__device__ __forceinline__ void mlp_mfma(
    const float* __restrict__ X, const unsigned short* __restrict__ W1t,
    const float* __restrict__ b1, const unsigned short* __restrict__ W2t,
    const float* __restrict__ b2, unsigned short* __restrict__ Y, int blk,
    int nrows, unsigned short* __restrict__ hl) {
  const int lane = threadIdx.x & 63;
  const int m = lane & 15;
  const int quad = lane >> 4;
  const int rowbase = blk * 64 + (threadIdx.x >> 6) * 16;

  // A fragments: X[rowbase+m][quad*8 + j], two K=32 tiles, fp32 -> bf16
  bf16x8 a0, a1;
  {
    float4 xa = {0.f, 0.f, 0.f, 0.f}, xb = xa, xc = xa, xd = xa;
    const int row = rowbase + m;
    if (row < nrows) {
      const float* xp = X + (size_t)row * DD + quad * 8;
      xa = *(const float4*)(xp);
      xb = *(const float4*)(xp + 4);
      xc = *(const float4*)(xp + 32);
      xd = *(const float4*)(xp + 36);
    }
    a0[0] = (short)f2bf(xa.x); a0[1] = (short)f2bf(xa.y);
    a0[2] = (short)f2bf(xa.z); a0[3] = (short)f2bf(xa.w);
    a0[4] = (short)f2bf(xb.x); a0[5] = (short)f2bf(xb.y);
    a0[6] = (short)f2bf(xb.z); a0[7] = (short)f2bf(xb.w);
    a1[0] = (short)f2bf(xc.x); a1[1] = (short)f2bf(xc.y);
    a1[2] = (short)f2bf(xc.z); a1[3] = (short)f2bf(xc.w);
    a1[4] = (short)f2bf(xd.x); a1[5] = (short)f2bf(xd.y);
    a1[6] = (short)f2bf(xd.z); a1[7] = (short)f2bf(xd.w);
  }

  // phase 1: 8 ntiles of H
#pragma unroll
  for (int nt = 0; nt < 8; ++nt) {
    const int n = nt * 16 + m;
    const float bv = b1[n];
    f32x4 acc = {bv, bv, bv, bv};
    const bf16x8 b0 = *(const bf16x8*)(W1t + n * 64 + quad * 8);
    const bf16x8 b1f = *(const bf16x8*)(W1t + n * 64 + 32 + quad * 8);
    acc = __builtin_amdgcn_mfma_f32_16x16x32_bf16(a0, b0, acc, 0, 0, 0);
    acc = __builtin_amdgcn_mfma_f32_16x16x32_bf16(a1, b1f, acc, 0, 0, 0);
#pragma unroll
    for (int r = 0; r < 4; ++r)
      hl[(quad * 4 + r) * HROW + n] = f2bf(fmaxf(acc[r], 0.f));
  }
  // wave-private H tile: no __syncthreads (in-wave LDS ordering)

  // phase 2 A fragments from H
  bf16x8 ha[4];
#pragma unroll
  for (int kc = 0; kc < 4; ++kc)
    ha[kc] = *(const bf16x8*)(hl + m * HROW + kc * 32 + quad * 8);

#pragma unroll
  for (int nt = 0; nt < 4; ++nt) {
    const int n = nt * 16 + m;
    const float bv = b2[n];
    f32x4 acc = {bv, bv, bv, bv};
#pragma unroll
    for (int kc = 0; kc < 4; ++kc) {
      const bf16x8 bw = *(const bf16x8*)(W2t + n * 128 + kc * 32 + quad * 8);
      acc = __builtin_amdgcn_mfma_f32_16x16x32_bf16(ha[kc], bw, acc, 0, 0, 0);
    }
#pragma unroll
    for (int r = 0; r < 4; ++r) {
      const int row = rowbase + quad * 4 + r;
      if (row < nrows) Y[(size_t)row * DD + n] = f2bf(acc[r]);
    }
  }
}

// ---------------------------------------------------------------------------
// MLP standalone kernel (de-fused from k1 for attribution + geometry):
// 256 threads / 64 rows per block, 17.4 KB LDS -> ~8 blocks/CU, 786 blocks
// over 256 CUs = balanced ~3 blocks/CU, no union-forced 69.6 KB allocation.
// ---------------------------------------------------------------------------
__global__ __launch_bounds__(256) void mlp_kernel(
    const float* __restrict__ x_v, const float* __restrict__ x_c,
    const float* __restrict__ b1v, const float* __restrict__ b2v,
    const float* __restrict__ b1c, const float* __restrict__ b2c,
    const unsigned short* __restrict__ wt, unsigned short* __restrict__ table) {
  __shared__ unsigned short hl4[4][16 * HROW];  // 17.4 KB
  const int mb = blockIdx.x;
  unsigned short* hl = hl4[threadIdx.x >> 6];
  if (mb < MLPV_B)
    mlp_mfma(x_v, wt, b1v, wt + 8192, b2v, table, mb, NN, hl);
  else
    mlp_mfma(x_c, wt + 16384, b1c, wt + 24576, b2c,
             table + (size_t)NN * DD, mb - MLPV_B, NC, hl);
}

// ---------------------------------------------------------------------------
// Fill standalone kernel, 1024 threads / 8192 edges per block: block-local
// counting sort into NB coarse buckets; ONE global atomic per (block,bucket)
// reserves a run at bucket*BCAP; bucket-ordered copy-out -> coalesced runs.
// Record = (d<<16)|s. r1 post-mortem: direct global scatter blew WRITE_SIZE
// to 80 MB (64B-line amplification) -- the sort IS the coalescing mechanism.
// Standalone: 36 KB LDS (no MLP union), 147 blocks -> one block per CU,
// makespan = single block time, no 2-block serial chains.
// ---------------------------------------------------------------------------
__global__ __launch_bounds__(1024) void fill_kernel(
    const int* __restrict__ src_vv, const int* __restrict__ dst_vv,
    const int* __restrict__ src_vc, const int* __restrict__ dst_vc,
    int* __restrict__ gcur, unsigned int* __restrict__ records) {
  __shared__ struct {
    int cnt[NB];
    int off[NB];
    int gbase[NB];
    int sa[256];                   // inclusive-scan output
    unsigned int stage[FILL_EPB];  // 32 KB
  } f;
  const int t = threadIdx.x;  // 0..1023
  const int base = blockIdx.x * FILL_EPB;
  if (t < NB) f.cnt[t] = 0;
  __syncthreads();

  unsigned int rec[8];
  int rk[8];
#pragma unroll
  for (int r = 0; r < 8; ++r) {
    const int e = base + r * 1024 + t;
    rk[r] = -1;
    if (e < NE) {
      int s, d;
      if (e < EVV) {
        s = src_vv[e];
        d = dst_vv[e];
      } else {
        s = NN + src_vc[e - EVV];
        d = dst_vc[e - EVV];
      }
      rec[r] = ((unsigned int)d << 16) | (unsigned int)s;
      rk[r] = atomicAdd(&f.cnt[d >> 8], 1);
    }
  }
  __syncthreads();

  // wave-0 inclusive scan over NB counters: 4 chunks of 64 lanes, shfl-based
  if (t < 64) {
    int carry = 0;
    for (int ch = 0; ch < 4; ++ch) {
      const int idx = ch * 64 + t;
      int v = (idx < NB) ? f.cnt[idx] : 0;
#pragma unroll
      for (int o = 1; o < 64; o <<= 1) {
        const int u = __shfl_up(v, o, 64);
        if (t >= o) v += u;
      }
      const int inc = v + carry;
      if (idx < NB) f.sa[idx] = inc;
      carry = __shfl(inc, 63, 64);
    }
  }
  __syncthreads();

  if (t < NB) {
    const int val = f.cnt[t];
    f.off[t] = f.sa[t] - val;
    f.gbase[t] = t * BCAP + ((val > 0) ? atomicAdd(&gcur[t], val) : 0);
  }
  __syncthreads();

#pragma unroll
  for (int r = 0; r < 8; ++r)
    if (rk[r] >= 0) f.stage[f.off[rec[r] >> 24] + rk[r]] = rec[r];
  __syncthreads();

  const int total = (NE - base < FILL_EPB) ? (NE - base) : FILL_EPB;
  for (int i = t; i < total; i += 1024) {
    const unsigned int u = f.stage[i];
    const int b2 = u >> 24;  // = d >> 8
    records[f.gbase[b2] + (i - f.off[b2])] = u;
  }
}

// ---------------------------------------------------------------------------
// Gather (r6 form, verified): two 1024-thread half-bucket blocks per bucket;
// scan records once, place into 16 KB LDS lists, ZROW-pad to multiple of 8,
// accumulate with full 8-deep batches only.
// ---------------------------------------------------------------------------
__device__ __forceinline__ void acc8(float* a, const uint4 t) {
  a[0] += __uint_as_float(t.x << 16);
  a[1] += __uint_as_float(t.x & 0xffff0000u);
  a[2] += __uint_as_float(t.y << 16);
  a[3] += __uint_as_float(t.y & 0xffff0000u);
  a[4] += __uint_as_float(t.z << 16);
  a[5] += __uint_as_float(t.z & 0xffff0000u);
  a[6] += __uint_as_float(t.w << 16);
  a[7] += __uint_as_float(t.w & 0xffff0000u);
}

__device__ __forceinline__ void place(unsigned int u, unsigned int hsel,
                                      int* c1, unsigned short* slots) {
  const unsigned int lv = (u >> 16) & 255u;
  if ((lv & 128u) == hsel) {
    const int lg = (int)(lv & 127u);
    const int pos = atomicAdd(&c1[lg], 1);
    if (pos < VCAP) slots[lg * VCAP + pos] = (unsigned short)(u & 0xffffu);
  }
}

__global__ __launch_bounds__(1024) void gather_kernel(
    const uint4* __restrict__ table4, const unsigned int* __restrict__ records,
    const int* __restrict__ gcur, const float4* __restrict__ xv4,
    float4* __restrict__ out4) {
  __shared__ int c1[128];
  __shared__ unsigned short slots[128 * VCAP];  // 16 KB
  const int t = threadIdx.x;  // 0..1023
  const int bucket = blockIdx.x >> 1;
  const unsigned int hsel = (blockIdx.x & 1) << 7;
  const int start = bucket * BCAP;
  const int nrec = gcur[bucket];
  const int g = t >> 3;  // 0..127
  const int c = t & 7;
  const int v = bucket * 256 + (int)hsel + g;
  const size_t ob = (size_t)v * 16 + c * 2;

  // prefetch x_v early: independent of the scan, hides HBM/L3 latency
  float4 x0 = {0.f, 0.f, 0.f, 0.f}, x1 = x0;
  if (v < NN) {
    x0 = xv4[ob];
    x1 = xv4[ob + 1];
  }

  if (t < 128) c1[t] = 0;
  __syncthreads();

  const uint4* rec4 = (const uint4*)(records + start);
  const int nfull = nrec >> 2;
  for (int q = t; q < nfull; q += 1024) {
    const uint4 u = rec4[q];
    place(u.x, hsel, c1, slots);
    place(u.y, hsel, c1, slots);
    place(u.z, hsel, c1, slots);
    place(u.w, hsel, c1, slots);
  }
  for (int j = (nfull << 2) + t; j < nrec; j += 1024)
    place(records[start + j], hsel, c1, slots);
  __syncthreads();

  // pad each list to a multiple of 8 with the zeros row
  if (t < 128) {
    int n = c1[t];
    n = (n > VCAP) ? VCAP : n;
    const int np = (n + 7) & ~7;
    for (int i = n; i < np; ++i) slots[t * VCAP + i] = (unsigned short)ZROW;
    c1[t] = np;
  }
  __syncthreads();

  if (v >= NN) return;
  const int n = c1[g];  // multiple of 8, <= 64
  const unsigned short* sl = slots + g * VCAP;

  float a[8];
#pragma unroll
  for (int r = 0; r < 8; ++r) a[r] = 0.f;

  for (int i = 0; i < n; i += 8) {
    const int e0 = sl[i + 0];
    const int e1 = sl[i + 1];
    const int e2 = sl[i + 2];
    const int e3 = sl[i + 3];
    const int e4 = sl[i + 4];
    const int e5 = sl[i + 5];
    const int e6 = sl[i + 6];
    const int e7 = sl[i + 7];
    const uint4 t0 = table4[(size_t)e0 * 8 + c];
    const uint4 t1 = table4[(size_t)e1 * 8 + c];
    const uint4 t2 = table4[(size_t)e2 * 8 + c];
    const uint4 t3 = table4[(size_t)e3 * 8 + c];
    const uint4 t4 = table4[(size_t)e4 * 8 + c];
    const uint4 t5 = table4[(size_t)e5 * 8 + c];
    const uint4 t6 = table4[(size_t)e6 * 8 + c];
    const uint4 t7 = table4[(size_t)e7 * 8 + c];
    acc8(a, t0); acc8(a, t1); acc8(a, t2); acc8(a, t3);
    acc8(a, t4); acc8(a, t5); acc8(a, t6); acc8(a, t7);
  }

  float4 o0, o1;
  o0.x = fmaxf(x0.x + a[0], 0.f);
  o0.y = fmaxf(x0.y + a[1], 0.f);
  o0.z = fmaxf(x0.z + a[2], 0.f);
  o0.w = fmaxf(x0.w + a[3], 0.f);
  o1.x = fmaxf(x1.x + a[4], 0.f);
  o1.y = fmaxf(x1.y + a[5], 0.f);
  o1.z = fmaxf(x1.z + a[6], 0.f);
  o1.w = fmaxf(x1.w + a[7], 0.f);
  out4[ob] = o0;
  out4[ob + 1] = o1;
}

extern "C" void kernel_launch(void* const* d_in, const int* in_sizes, int n_in,
                              void* d_out, int out_size, void* d_ws,
                              size_t ws_size, hipStream_t stream) {
  const float* x_v = (const float*)d_in[0];
  const float* x_c = (const float*)d_in[1];
  const float* W1v = (const float*)d_in[2];
  const float* b1v = (const float*)d_in[3];
  const float* W2v = (const float*)d_in[4];
  const float* b2v = (const float*)d_in[5];
  const float* W1c = (const float*)d_in[6];
  const float* b1c = (const float*)d_in[7];
  const float* W2c = (const float*)d_in[8];
  const float* b2c = (const float*)d_in[9];
  const int* src_vv = (const int*)d_in[10];
  const int* dst_vv = (const int*)d_in[11];
  const int* src_vc = (const int*)d_in[12];
  const int* dst_vc = (const int*)d_in[13];
  float* out = (float*)d_out;

  // workspace: table(bf16, +1 zeros row) | records 6.42 MB | wt 64 KB | gcur
  char* p = (char*)d_ws;
  unsigned short* table = (unsigned short*)p;
  p += (size_t)(NN + NC + 1) * DD * sizeof(unsigned short);
  unsigned int* records = (unsigned int*)p;
  p += (size_t)NB * BCAP * sizeof(unsigned int);
  unsigned short* wt = (unsigned short*)p;
  p += (size_t)4 * 8192 * sizeof(unsigned short);
  int* gcur = (int*)p;

  prep_kernel<<<128, 256, 0, stream>>>(W1v, W2v, W1c, W2c, wt, gcur, table);

  fill_kernel<<<FILL_B, 1024, 0, stream>>>(src_vv, dst_vv, src_vc, dst_vc,
                                           gcur, records);

  mlp_kernel<<<MLP_B, 256, 0, stream>>>(x_v, x_c, b1v, b2v, b1c, b2c, wt,
                                        table);

  gather_kernel<<<GAT_B, 1024, 0, stream>>>((const uint4*)table, records, gcur,
                                            (const float4*)x_v, (float4*)out);
}

// Round 8
// 136.521 us; speedup vs baseline: 1.0430x; 1.0430x over previous
//
#include <hip/hip_runtime.h>

#define NN 50000
#define NC 256
#define DD 64
#define HH 128
#define EVV 800000
#define EVC 400000
#define NE 1200000
#define NHB 391             // half-buckets of 128 vertices (d>>7); 49999>>7=390
#define BCAP 4096           // records per half-bucket; mean 3072, +18.5 sigma
#define MLPV_B 196          // ceil(NN/256)  (256 rows/block, 16/wave via MFMA)
#define MLPC_B 1            // NC/256
#define MLP_B (MLPV_B + MLPC_B)   // 197
#define FILL_EPB 8192       // edges per fill block (1024 thr x 8)
#define FILL_B 147          // ceil(NE/8192)
#define SEPT 50             // septets: covers ceil(147/3)=49 fill, ceil(197/4)=50 mlp
#define K1_B (SEPT * 7)     // 350 blocks, period-7: {3 fill, 4 mlp}
#define GAT_B NHB           // one block per half-bucket
#define VCAP 64             // slots per vertex; Poisson(24), P(>64) ~ 1e-11
#define ZROW (NN + NC)      // zeros table row used for list padding (50256)
#define HROW 136            // H-tile row pitch (128 + 8 pad: kills bank conflicts)

typedef __attribute__((ext_vector_type(8))) short bf16x8;
typedef __attribute__((ext_vector_type(4))) float f32x4;

__device__ __forceinline__ unsigned short f2bf(float x) {
  unsigned u = __float_as_uint(x);
  u = (u + 0x7fffu + ((u >> 16) & 1u)) >> 16;  // round-to-nearest-even
  return (unsigned short)u;
}

// LDS overlay: mfma-mlp H tiles (69.6 KB, 16 waves) and fill (~38.4 KB)
// never coexist. 69.6 KB/block -> 2 blocks/CU; grid 350 fully co-resident.
union SMem {
  unsigned short hl[16][16 * HROW];  // per-wave H tile, 4352 B each
  struct {
    int cnt[NHB];
    int off[NHB];
    int gbase[NHB];
    int sa[448];                   // inclusive-scan output (7 x 64)
    unsigned int stage[FILL_EPB];  // 32 KB
  } f;
};

// ---------------------------------------------------------------------------
// Weight prep + gcur zero + table zero-row (used to pad gather lists).
// wt layout: W1t_v [128][64] | W2t_v [64][128] | W1t_c | W2t_c  (8192 each)
// W1t[n][k] = bf16(W1[k][n]); W2t[n][k] = bf16(W2[k][n]).
// ---------------------------------------------------------------------------
__global__ __launch_bounds__(256) void prep_kernel(
    const float* __restrict__ W1v, const float* __restrict__ W2v,
    const float* __restrict__ W1c, const float* __restrict__ W2c,
    unsigned short* __restrict__ wt, int* __restrict__ gcur,
    unsigned short* __restrict__ table) {
  const int tid = blockIdx.x * 256 + threadIdx.x;  // 0..32767
  if (tid < NHB) gcur[tid] = 0;
  if (tid < DD) table[(size_t)ZROW * DD + tid] = 0;  // zeros row for padding
  const int sel = tid >> 13;
  const int t = tid & 8191;
  unsigned short* dst = wt + sel * 8192;
  if (sel == 0) {
    const int n = t >> 6, k = t & 63;
    dst[t] = f2bf(W1v[k * HH + n]);
  } else if (sel == 1) {
    const int n = t >> 7, k = t & 127;
    dst[t] = f2bf(W2v[k * DD + n]);
  } else if (sel == 2) {
    const int n = t >> 6, k = t & 63;
    dst[t] = f2bf(W1c[k * HH + n]);
  } else {
    const int n = t >> 7, k = t & 127;
    dst[t] = f2bf(W2c[k * DD + n]);
  }
}

// ---------------------------------------------------------------------------
// MFMA MLP, 16 rows per wave (16 waves -> 256 rows/block):
//   H[16x128] = relu(X[16x64] @ W1 + b1)   -- 8 ntiles x 2 mfma_16x16x32_bf16
//   O[16x64]  = H @ W2 + b2                -- 4 ntiles x 4 mfma
// Fragment layouts (verified m89/m120): A[m=lane&15][k=quad*8+j],
// B[k=quad*8+j][n=lane&15], C/D col=lane&15 row=quad*4+reg.
// H transposes C->A layout through a wave-private padded LDS tile (no
// barrier: in-wave lgkmcnt ordering suffices -- validated r14).
// ---------------------------------------------------------------------------
__device__ __forceinline__ void mlp_mfma(
    const float* __restrict__ X, const unsigned short* __restrict__ W1t,
    const float* __restrict__ b1, const unsigned short* __restrict__ W2t,
    const float* __restrict__ b2, unsigned short* __restrict__ Y, int blk,
    int nrows, unsigned short* __restrict__ hl) {
  const int lane = threadIdx.x & 63;
  const int m = lane & 15;
  const int quad = lane >> 4;
  const int rowbase = blk * 256 + (threadIdx.x >> 6) * 16;

  // A fragments: X[rowbase+m][quad*8 + j], two K=32 tiles, fp32 -> bf16
  bf16x8 a0, a1;
  {
    float4 xa = {0.f, 0.f, 0.f, 0.f}, xb = xa, xc = xa, xd = xa;
    const int row = rowbase + m;
    if (row < nrows) {
      const float* xp = X + (size_t)row * DD + quad * 8;
      xa = *(const float4*)(xp);
      xb = *(const float4*)(xp + 4);
      xc = *(const float4*)(xp + 32);
      xd = *(const float4*)(xp + 36);
    }
    a0[0] = (short)f2bf(xa.x); a0[1] = (short)f2bf(xa.y);
    a0[2] = (short)f2bf(xa.z); a0[3] = (short)f2bf(xa.w);
    a0[4] = (short)f2bf(xb.x); a0[5] = (short)f2bf(xb.y);
    a0[6] = (short)f2bf(xb.z); a0[7] = (short)f2bf(xb.w);
    a1[0] = (short)f2bf(xc.x); a1[1] = (short)f2bf(xc.y);
    a1[2] = (short)f2bf(xc.z); a1[3] = (short)f2bf(xc.w);
    a1[4] = (short)f2bf(xd.x); a1[5] = (short)f2bf(xd.y);
    a1[6] = (short)f2bf(xd.z); a1[7] = (short)f2bf(xd.w);
  }

  // phase 1: 8 ntiles of H
#pragma unroll
  for (int nt = 0; nt < 8; ++nt) {
    const int n = nt * 16 + m;
    const float bv = b1[n];
    f32x4 acc = {bv, bv, bv, bv};
    const bf16x8 b0 = *(const bf16x8*)(W1t + n * 64 + quad * 8);
    const bf16x8 b1f = *(const bf16x8*)(W1t + n * 64 + 32 + quad * 8);
    acc = __builtin_amdgcn_mfma_f32_16x16x32_bf16(a0, b0, acc, 0, 0, 0);
    acc = __builtin_amdgcn_mfma_f32_16x16x32_bf16(a1, b1f, acc, 0, 0, 0);
#pragma unroll
    for (int r = 0; r < 4; ++r)
      hl[(quad * 4 + r) * HROW + n] = f2bf(fmaxf(acc[r], 0.f));
  }
  // wave-private H tile: no __syncthreads (in-wave LDS ordering)

  // phase 2 A fragments from H
  bf16x8 ha[4];
#pragma unroll
  for (int kc = 0; kc < 4; ++kc)
    ha[kc] = *(const bf16x8*)(hl + m * HROW + kc * 32 + quad * 8);

#pragma unroll
  for (int nt = 0; nt < 4; ++nt) {
    const int n = nt * 16 + m;
    const float bv = b2[n];
    f32x4 acc = {bv, bv, bv, bv};
#pragma unroll
    for (int kc = 0; kc < 4; ++kc) {
      const bf16x8 bw = *(const bf16x8*)(W2t + n * 128 + kc * 32 + quad * 8);
      acc = __builtin_amdgcn_mfma_f32_16x16x32_bf16(ha[kc], bw, acc, 0, 0, 0);
    }
#pragma unroll
    for (int r = 0; r < 4; ++r) {
      const int row = rowbase + quad * 4 + r;
      if (row < nrows) Y[(size_t)row * DD + n] = f2bf(acc[r]);
    }
  }
}

// ---------------------------------------------------------------------------
// Fill branch, 1024 threads / 8192 edges per block: block-local counting
// sort into NHB HALF-bucket regions (d>>7, 128 vertices each); ONE global
// atomic per (block,half-bucket) reserves a run at hb*BCAP; ordered copy-out
// -> coalesced runs. Record = (d<<16)|s. r1 post-mortem: direct global
// scatter blew WRITE_SIZE to 80 MB -- the sort IS the coalescing mechanism.
// Half-bucket keying lets each gather block read exactly its own records
// (halves gather scan bytes + place work vs 256-vertex buckets).
// ---------------------------------------------------------------------------
__device__ __forceinline__ void fill_block(
    const int* __restrict__ src_vv, const int* __restrict__ dst_vv,
    const int* __restrict__ src_vc, const int* __restrict__ dst_vc,
    int* __restrict__ gcur, unsigned int* __restrict__ records, int blk,
    SMem* sm) {
  const int t = threadIdx.x;  // 0..1023
  const int base = blk * FILL_EPB;
  if (t < NHB) sm->f.cnt[t] = 0;
  __syncthreads();

  unsigned int rec[8];
  int rk[8];
#pragma unroll
  for (int r = 0; r < 8; ++r) {
    const int e = base + r * 1024 + t;
    rk[r] = -1;
    if (e < NE) {
      int s, d;
      if (e < EVV) {
        s = src_vv[e];
        d = dst_vv[e];
      } else {
        s = NN + src_vc[e - EVV];
        d = dst_vc[e - EVV];
      }
      rec[r] = ((unsigned int)d << 16) | (unsigned int)s;
      rk[r] = atomicAdd(&sm->f.cnt[d >> 7], 1);
    }
  }
  __syncthreads();

  // wave-0 inclusive scan over NHB counters: 7 chunks of 64 lanes, shfl-based
  if (t < 64) {
    int carry = 0;
    for (int ch = 0; ch < 7; ++ch) {
      const int idx = ch * 64 + t;
      int v = (idx < NHB) ? sm->f.cnt[idx] : 0;
#pragma unroll
      for (int o = 1; o < 64; o <<= 1) {
        const int u = __shfl_up(v, o, 64);
        if (t >= o) v += u;
      }
      const int inc = v + carry;
      if (idx < 448) sm->f.sa[idx] = inc;
      carry = __shfl(inc, 63, 64);
    }
  }
  __syncthreads();

  if (t < NHB) {
    const int val = sm->f.cnt[t];
    sm->f.off[t] = sm->f.sa[t] - val;
    sm->f.gbase[t] = t * BCAP + ((val > 0) ? atomicAdd(&gcur[t], val) : 0);
  }
  __syncthreads();

#pragma unroll
  for (int r = 0; r < 8; ++r)
    if (rk[r] >= 0) sm->f.stage[sm->f.off[rec[r] >> 23] + rk[r]] = rec[r];
  __syncthreads();

  const int total = (NE - base < FILL_EPB) ? (NE - base) : FILL_EPB;
  for (int i = t; i < total; i += 1024) {
    const unsigned int u = sm->f.stage[i];
    const int b2 = u >> 23;  // = d >> 7
    records[sm->f.gbase[b2] + (i - sm->f.off[b2])] = u;
  }
}

// ---------------------------------------------------------------------------
// K1 fused, INTERLEAVED period-7: {3 fill, 4 mfma-mlp} per septet.
// (r7 de-fusion cost +4.4 us -- the fused overlap is real; restored.)
// ---------------------------------------------------------------------------
__global__ __launch_bounds__(1024) void k1_kernel(
    const float* __restrict__ x_v, const float* __restrict__ x_c,
    const float* __restrict__ b1v, const float* __restrict__ b2v,
    const float* __restrict__ b1c, const float* __restrict__ b2c,
    const unsigned short* __restrict__ wt,
    const int* __restrict__ src_vv, const int* __restrict__ dst_vv,
    const int* __restrict__ src_vc, const int* __restrict__ dst_vc,
    unsigned short* __restrict__ table, int* __restrict__ gcur,
    unsigned int* __restrict__ records) {
  __shared__ SMem sm;
  const int q = blockIdx.x / 7;
  const int r = blockIdx.x % 7;
  if (r < 3) {
    const int fid = q * 3 + r;
    if (fid >= FILL_B) return;
    fill_block(src_vv, dst_vv, src_vc, dst_vc, gcur, records, fid, &sm);
  } else {
    const int mb = q * 4 + (r - 3);
    if (mb >= MLP_B) return;
    unsigned short* hl = sm.hl[threadIdx.x >> 6];
    if (mb < MLPV_B)
      mlp_mfma(x_v, wt, b1v, wt + 8192, b2v, table, mb, NN, hl);
    else
      mlp_mfma(x_c, wt + 16384, b1c, wt + 24576, b2c,
               table + (size_t)NN * DD, mb - MLPV_B, NC, hl);
  }
}

// ---------------------------------------------------------------------------
// Gather: ONE 1024-thread block per half-bucket (391 blocks). Reads EXACTLY
// its own ~3072 records (no filtering, no discarded work -- was 2x scan +
// 50% discarded place in the 256-vertex-bucket form). Places into 16 KB LDS
// slot lists for 128 vertices, ZROW-pads to multiples of 8, accumulates
// with full 8-deep batches only.
// ---------------------------------------------------------------------------
__device__ __forceinline__ void acc8(float* a, const uint4 t) {
  a[0] += __uint_as_float(t.x << 16);
  a[1] += __uint_as_float(t.x & 0xffff0000u);
  a[2] += __uint_as_float(t.y << 16);
  a[3] += __uint_as_float(t.y & 0xffff0000u);
  a[4] += __uint_as_float(t.z << 16);
  a[5] += __uint_as_float(t.z & 0xffff0000u);
  a[6] += __uint_as_float(t.w << 16);
  a[7] += __uint_as_float(t.w & 0xffff0000u);
}

__device__ __forceinline__ void place(unsigned int u, int* c1,
                                      unsigned short* slots) {
  const int lv = (int)((u >> 16) & 127u);
  const int pos = atomicAdd(&c1[lv], 1);
  if (pos < VCAP) slots[lv * VCAP + pos] = (unsigned short)(u & 0xffffu);
}

__global__ __launch_bounds__(1024) void gather_kernel(
    const uint4* __restrict__ table4, const unsigned int* __restrict__ records,
    const int* __restrict__ gcur, const float4* __restrict__ xv4,
    float4* __restrict__ out4) {
  __shared__ int c1[128];
  __shared__ unsigned short slots[128 * VCAP];  // 16 KB
  const int t = threadIdx.x;  // 0..1023
  const int hb = blockIdx.x;
  const int start = hb * BCAP;
  const int nrec = gcur[hb];
  const int g = t >> 3;  // 0..127
  const int c = t & 7;
  const int v = hb * 128 + g;
  const size_t ob = (size_t)v * 16 + c * 2;

  // prefetch x_v early: independent of the scan, hides HBM/L3 latency
  float4 x0 = {0.f, 0.f, 0.f, 0.f}, x1 = x0;
  if (v < NN) {
    x0 = xv4[ob];
    x1 = xv4[ob + 1];
  }

  if (t < 128) c1[t] = 0;
  __syncthreads();

  const uint4* rec4 = (const uint4*)(records + start);
  const int nfull = nrec >> 2;
  for (int q = t; q < nfull; q += 1024) {
    const uint4 u = rec4[q];
    place(u.x, c1, slots);
    place(u.y, c1, slots);
    place(u.z, c1, slots);
    place(u.w, c1, slots);
  }
  for (int j = (nfull << 2) + t; j < nrec; j += 1024)
    place(records[start + j], c1, slots);
  __syncthreads();

  // pad each list to a multiple of 8 with the zeros row
  if (t < 128) {
    int n = c1[t];
    n = (n > VCAP) ? VCAP : n;
    const int np = (n + 7) & ~7;
    for (int i = n; i < np; ++i) slots[t * VCAP + i] = (unsigned short)ZROW;
    c1[t] = np;
  }
  __syncthreads();

  if (v >= NN) return;
  const int n = c1[g];  // multiple of 8, <= 64
  const unsigned short* sl = slots + g * VCAP;

  float a[8];
#pragma unroll
  for (int r = 0; r < 8; ++r) a[r] = 0.f;

  for (int i = 0; i < n; i += 8) {
    const int e0 = sl[i + 0];
    const int e1 = sl[i + 1];
    const int e2 = sl[i + 2];
    const int e3 = sl[i + 3];
    const int e4 = sl[i + 4];
    const int e5 = sl[i + 5];
    const int e6 = sl[i + 6];
    const int e7 = sl[i + 7];
    const uint4 t0 = table4[(size_t)e0 * 8 + c];
    const uint4 t1 = table4[(size_t)e1 * 8 + c];
    const uint4 t2 = table4[(size_t)e2 * 8 + c];
    const uint4 t3 = table4[(size_t)e3 * 8 + c];
    const uint4 t4 = table4[(size_t)e4 * 8 + c];
    const uint4 t5 = table4[(size_t)e5 * 8 + c];
    const uint4 t6 = table4[(size_t)e6 * 8 + c];
    const uint4 t7 = table4[(size_t)e7 * 8 + c];
    acc8(a, t0); acc8(a, t1); acc8(a, t2); acc8(a, t3);
    acc8(a, t4); acc8(a, t5); acc8(a, t6); acc8(a, t7);
  }

  float4 o0, o1;
  o0.x = fmaxf(x0.x + a[0], 0.f);
  o0.y = fmaxf(x0.y + a[1], 0.f);
  o0.z = fmaxf(x0.z + a[2], 0.f);
  o0.w = fmaxf(x0.w + a[3], 0.f);
  o1.x = fmaxf(x1.x + a[4], 0.f);
  o1.y = fmaxf(x1.y + a[5], 0.f);
  o1.z = fmaxf(x1.z + a[6], 0.f);
  o1.w = fmaxf(x1.w + a[7], 0.f);
  out4[ob] = o0;
  out4[ob + 1] = o1;
}

extern "C" void kernel_launch(void* const* d_in, const int* in_sizes, int n_in,
                              void* d_out, int out_size, void* d_ws,
                              size_t ws_size, hipStream_t stream) {
  const float* x_v = (const float*)d_in[0];
  const float* x_c = (const float*)d_in[1];
  const float* W1v = (const float*)d_in[2];
  const float* b1v = (const float*)d_in[3];
  const float* W2v = (const float*)d_in[4];
  const float* b2v = (const float*)d_in[5];
  const float* W1c = (const float*)d_in[6];
  const float* b1c = (const float*)d_in[7];
  const float* W2c = (const float*)d_in[8];
  const float* b2c = (const float*)d_in[9];
  const int* src_vv = (const int*)d_in[10];
  const int* dst_vv = (const int*)d_in[11];
  const int* src_vc = (const int*)d_in[12];
  const int* dst_vc = (const int*)d_in[13];
  float* out = (float*)d_out;

  // workspace: table(bf16, +1 zeros row) | records 6.40 MB | wt 64 KB | gcur
  char* p = (char*)d_ws;
  unsigned short* table = (unsigned short*)p;
  p += (size_t)(NN + NC + 1) * DD * sizeof(unsigned short);
  unsigned int* records = (unsigned int*)p;
  p += (size_t)NHB * BCAP * sizeof(unsigned int);
  unsigned short* wt = (unsigned short*)p;
  p += (size_t)4 * 8192 * sizeof(unsigned short);
  int* gcur = (int*)p;

  prep_kernel<<<128, 256, 0, stream>>>(W1v, W2v, W1c, W2c, wt, gcur, table);

  k1_kernel<<<K1_B, 1024, 0, stream>>>(x_v, x_c, b1v, b2v, b1c, b2c, wt,
                                       src_vv, dst_vv, src_vc, dst_vc, table,
                                       gcur, records);

  gather_kernel<<<GAT_B, 1024, 0, stream>>>((const uint4*)table, records, gcur,
                                            (const float4*)x_v, (float4*)out);
}

// Round 10
// 135.497 us; speedup vs baseline: 1.0509x; 1.0076x over previous
//
#include <hip/hip_runtime.h>

#define NN 50000
#define NC 256
#define DD 64
#define HH 128
#define EVV 800000
#define EVC 400000
#define NE 1200000
#define NHB 391             // half-buckets of 128 vertices (d>>7); 49999>>7=390
#define BCAP 4096           // records per half-bucket; mean 3072, +18.5 sigma
#define MLPV_B 196          // ceil(NN/256)  (256 rows/block, 16/wave via MFMA)
#define MLPC_B 1            // NC/256
#define MLP_B (MLPV_B + MLPC_B)   // 197
#define FILL_EPB 8192       // edges per fill block (1024 thr x 8)
#define FILL_B 147          // ceil(NE/8192)
#define SEPT 50             // septets: covers ceil(147/3)=49 fill, ceil(197/4)=50 mlp
#define K1_B (SEPT * 7)     // 350 blocks, period-7: {3 fill, 4 mlp}
#define GAT_B NHB           // one block per half-bucket
#define VCAP 64             // slots per vertex; Poisson(24), P(>64) ~ 1e-11
#define ZROW (NN + NC)      // zeros table row used for list padding (50256)
#define HROW 136            // H-tile row pitch (128 + 8 pad: kills bank conflicts)

typedef __attribute__((ext_vector_type(8))) short bf16x8;
typedef __attribute__((ext_vector_type(4))) float f32x4;

__device__ __forceinline__ unsigned short f2bf(float x) {
  unsigned u = __float_as_uint(x);
  u = (u + 0x7fffu + ((u >> 16) & 1u)) >> 16;  // round-to-nearest-even
  return (unsigned short)u;
}

// LDS overlay: mfma-mlp H tiles (69.6 KB, 16 waves) and fill (~38.4 KB)
// never coexist. 69.6 KB/block -> 2 blocks/CU; grid 350 fully co-resident.
union SMem {
  unsigned short hl[16][16 * HROW];  // per-wave H tile, 4352 B each
  struct {
    int cnt[NHB];
    int off[NHB];
    int gbase[NHB];
    int sa[448];                   // inclusive-scan output (7 x 64)
    unsigned int stage[FILL_EPB];  // 32 KB
  } f;
};

// ---------------------------------------------------------------------------
// Weight prep + gcur zero + table zero-row (used to pad gather lists).
// wt layout: W1t_v [128][64] | W2t_v [64][128] | W1t_c | W2t_c  (8192 each)
// W1t[n][k] = bf16(W1[k][n]); W2t[n][k] = bf16(W2[k][n]).
// NOTE (r9 post-mortem): prep must stay a separate launch -- the wt->mlp and
// table->gather producer/consumer edges cross XCDs, and per-XCD L2s are not
// coherent for plain loads/stores; only kernel boundaries flush reliably.
// ---------------------------------------------------------------------------
__global__ __launch_bounds__(256) void prep_kernel(
    const float* __restrict__ W1v, const float* __restrict__ W2v,
    const float* __restrict__ W1c, const float* __restrict__ W2c,
    unsigned short* __restrict__ wt, int* __restrict__ gcur,
    unsigned short* __restrict__ table) {
  const int tid = blockIdx.x * 256 + threadIdx.x;  // 0..32767
  if (tid < NHB) gcur[tid] = 0;
  if (tid < DD) table[(size_t)ZROW * DD + tid] = 0;  // zeros row for padding
  const int sel = tid >> 13;
  const int t = tid & 8191;
  unsigned short* dst = wt + sel * 8192;
  if (sel == 0) {
    const int n = t >> 6, k = t & 63;
    dst[t] = f2bf(W1v[k * HH + n]);
  } else if (sel == 1) {
    const int n = t >> 7, k = t & 127;
    dst[t] = f2bf(W2v[k * DD + n]);
  } else if (sel == 2) {
    const int n = t >> 6, k = t & 63;
    dst[t] = f2bf(W1c[k * HH + n]);
  } else {
    const int n = t >> 7, k = t & 127;
    dst[t] = f2bf(W2c[k * DD + n]);
  }
}

// ---------------------------------------------------------------------------
// MFMA MLP, 16 rows per wave (16 waves -> 256 rows/block):
//   H[16x128] = relu(X[16x64] @ W1 + b1)   -- 8 ntiles x 2 mfma_16x16x32_bf16
//   O[16x64]  = H @ W2 + b2                -- 4 ntiles x 4 mfma
// Fragment layouts (verified m89/m120): A[m=lane&15][k=quad*8+j],
// B[k=quad*8+j][n=lane&15], C/D col=lane&15 row=quad*4+reg.
// H transposes C->A layout through a wave-private padded LDS tile (no
// barrier: in-wave lgkmcnt ordering suffices -- validated r14).
// ---------------------------------------------------------------------------
__device__ __forceinline__ void mlp_mfma(
    const float* __restrict__ X, const unsigned short* __restrict__ W1t,
    const float* __restrict__ b1, const unsigned short* __restrict__ W2t,
    const float* __restrict__ b2, unsigned short* __restrict__ Y, int blk,
    int nrows, unsigned short* __restrict__ hl) {
  const int lane = threadIdx.x & 63;
  const int m = lane & 15;
  const int quad = lane >> 4;
  const int rowbase = blk * 256 + (threadIdx.x >> 6) * 16;

  // A fragments: X[rowbase+m][quad*8 + j], two K=32 tiles, fp32 -> bf16
  bf16x8 a0, a1;
  {
    float4 xa = {0.f, 0.f, 0.f, 0.f}, xb = xa, xc = xa, xd = xa;
    const int row = rowbase + m;
    if (row < nrows) {
      const float* xp = X + (size_t)row * DD + quad * 8;
      xa = *(const float4*)(xp);
      xb = *(const float4*)(xp + 4);
      xc = *(const float4*)(xp + 32);
      xd = *(const float4*)(xp + 36);
    }
    a0[0] = (short)f2bf(xa.x); a0[1] = (short)f2bf(xa.y);
    a0[2] = (short)f2bf(xa.z); a0[3] = (short)f2bf(xa.w);
    a0[4] = (short)f2bf(xb.x); a0[5] = (short)f2bf(xb.y);
    a0[6] = (short)f2bf(xb.z); a0[7] = (short)f2bf(xb.w);
    a1[0] = (short)f2bf(xc.x); a1[1] = (short)f2bf(xc.y);
    a1[2] = (short)f2bf(xc.z); a1[3] = (short)f2bf(xc.w);
    a1[4] = (short)f2bf(xd.x); a1[5] = (short)f2bf(xd.y);
    a1[6] = (short)f2bf(xd.z); a1[7] = (short)f2bf(xd.w);
  }

  // phase 1: 8 ntiles of H
#pragma unroll
  for (int nt = 0; nt < 8; ++nt) {
    const int n = nt * 16 + m;
    const float bv = b1[n];
    f32x4 acc = {bv, bv, bv, bv};
    const bf16x8 b0 = *(const bf16x8*)(W1t + n * 64 + quad * 8);
    const bf16x8 b1f = *(const bf16x8*)(W1t + n * 64 + 32 + quad * 8);
    acc = __builtin_amdgcn_mfma_f32_16x16x32_bf16(a0, b0, acc, 0, 0, 0);
    acc = __builtin_amdgcn_mfma_f32_16x16x32_bf16(a1, b1f, acc, 0, 0, 0);
#pragma unroll
    for (int r = 0; r < 4; ++r)
      hl[(quad * 4 + r) * HROW + n] = f2bf(fmaxf(acc[r], 0.f));
  }
  // wave-private H tile: no __syncthreads (in-wave LDS ordering)

  // phase 2 A fragments from H
  bf16x8 ha[4];
#pragma unroll
  for (int kc = 0; kc < 4; ++kc)
    ha[kc] = *(const bf16x8*)(hl + m * HROW + kc * 32 + quad * 8);

#pragma unroll
  for (int nt = 0; nt < 4; ++nt) {
    const int n = nt * 16 + m;
    const float bv = b2[n];
    f32x4 acc = {bv, bv, bv, bv};
#pragma unroll
    for (int kc = 0; kc < 4; ++kc) {
      const bf16x8 bw = *(const bf16x8*)(W2t + n * 128 + kc * 32 + quad * 8);
      acc = __builtin_amdgcn_mfma_f32_16x16x32_bf16(ha[kc], bw, acc, 0, 0, 0);
    }
#pragma unroll
    for (int r = 0; r < 4; ++r) {
      const int row = rowbase + quad * 4 + r;
      if (row < nrows) Y[(size_t)row * DD + n] = f2bf(acc[r]);
    }
  }
}

// ---------------------------------------------------------------------------
// Fill branch, 1024 threads / 8192 edges per block: block-local counting
// sort into NHB HALF-bucket regions (d>>7, 128 vertices each); ONE global
// atomic per (block,half-bucket) reserves a run at hb*BCAP; ordered copy-out
// -> coalesced runs. Record = (d<<16)|s. r1 post-mortem: direct global
// scatter blew WRITE_SIZE to 80 MB -- the sort IS the coalescing mechanism.
// Half-bucket keying lets each gather block read exactly its own records
// (halves gather scan bytes + place work vs 256-vertex buckets).
// ---------------------------------------------------------------------------
__device__ __forceinline__ void fill_block(
    const int* __restrict__ src_vv, const int* __restrict__ dst_vv,
    const int* __restrict__ src_vc, const int* __restrict__ dst_vc,
    int* __restrict__ gcur, unsigned int* __restrict__ records, int blk,
    SMem* sm) {
  const int t = threadIdx.x;  // 0..1023
  const int base = blk * FILL_EPB;
  if (t < NHB) sm->f.cnt[t] = 0;
  __syncthreads();

  unsigned int rec[8];
  int rk[8];
#pragma unroll
  for (int r = 0; r < 8; ++r) {
    const int e = base + r * 1024 + t;
    rk[r] = -1;
    if (e < NE) {
      int s, d;
      if (e < EVV) {
        s = src_vv[e];
        d = dst_vv[e];
      } else {
        s = NN + src_vc[e - EVV];
        d = dst_vc[e - EVV];
      }
      rec[r] = ((unsigned int)d << 16) | (unsigned int)s;
      rk[r] = atomicAdd(&sm->f.cnt[d >> 7], 1);
    }
  }
  __syncthreads();

  // wave-0 inclusive scan over NHB counters: 7 chunks of 64 lanes, shfl-based
  if (t < 64) {
    int carry = 0;
    for (int ch = 0; ch < 7; ++ch) {
      const int idx = ch * 64 + t;
      int v = (idx < NHB) ? sm->f.cnt[idx] : 0;
#pragma unroll
      for (int o = 1; o < 64; o <<= 1) {
        const int u = __shfl_up(v, o, 64);
        if (t >= o) v += u;
      }
      const int inc = v + carry;
      if (idx < 448) sm->f.sa[idx] = inc;
      carry = __shfl(inc, 63, 64);
    }
  }
  __syncthreads();

  if (t < NHB) {
    const int val = sm->f.cnt[t];
    sm->f.off[t] = sm->f.sa[t] - val;
    sm->f.gbase[t] = t * BCAP + ((val > 0) ? atomicAdd(&gcur[t], val) : 0);
  }
  __syncthreads();

#pragma unroll
  for (int r = 0; r < 8; ++r)
    if (rk[r] >= 0) sm->f.stage[sm->f.off[rec[r] >> 23] + rk[r]] = rec[r];
  __syncthreads();

  const int total = (NE - base < FILL_EPB) ? (NE - base) : FILL_EPB;
  for (int i = t; i < total; i += 1024) {
    const unsigned int u = sm->f.stage[i];
    const int b2 = u >> 23;  // = d >> 7
    records[sm->f.gbase[b2] + (i - sm->f.off[b2])] = u;
  }
}

// ---------------------------------------------------------------------------
// K1 fused, INTERLEAVED period-7: {3 fill, 4 mfma-mlp} per septet.
// (r7 de-fusion cost +4.4 us -- the fused overlap is real.)
// ---------------------------------------------------------------------------
__global__ __launch_bounds__(1024) void k1_kernel(
    const float* __restrict__ x_v, const float* __restrict__ x_c,
    const float* __restrict__ b1v, const float* __restrict__ b2v,
    const float* __restrict__ b1c, const float* __restrict__ b2c,
    const unsigned short* __restrict__ wt,
    const int* __restrict__ src_vv, const int* __restrict__ dst_vv,
    const int* __restrict__ src_vc, const int* __restrict__ dst_vc,
    unsigned short* __restrict__ table, int* __restrict__ gcur,
    unsigned int* __restrict__ records) {
  __shared__ SMem sm;
  const int q = blockIdx.x / 7;
  const int r = blockIdx.x % 7;
  if (r < 3) {
    const int fid = q * 3 + r;
    if (fid >= FILL_B) return;
    fill_block(src_vv, dst_vv, src_vc, dst_vc, gcur, records, fid, &sm);
  } else {
    const int mb = q * 4 + (r - 3);
    if (mb >= MLP_B) return;
    unsigned short* hl = sm.hl[threadIdx.x >> 6];
    if (mb < MLPV_B)
      mlp_mfma(x_v, wt, b1v, wt + 8192, b2v, table, mb, NN, hl);
    else
      mlp_mfma(x_c, wt + 16384, b1c, wt + 24576, b2c,
               table + (size_t)NN * DD, mb - MLPV_B, NC, hl);
  }
}

// ---------------------------------------------------------------------------
// Gather: ONE 1024-thread block per half-bucket (391 blocks). Reads EXACTLY
// its own ~3072 records (no filtering, no discarded work). Places into
// 16 KB LDS slot lists for 128 vertices, ZROW-pads to multiples of 8,
// accumulates with full 8-deep batches only.
// ---------------------------------------------------------------------------
__device__ __forceinline__ void acc8(float* a, const uint4 t) {
  a[0] += __uint_as_float(t.x << 16);
  a[1] += __uint_as_float(t.x & 0xffff0000u);
  a[2] += __uint_as_float(t.y << 16);
  a[3] += __uint_as_float(t.y & 0xffff0000u);
  a[4] += __uint_as_float(t.z << 16);
  a[5] += __uint_as_float(t.z & 0xffff0000u);
  a[6] += __uint_as_float(t.w << 16);
  a[7] += __uint_as_float(t.w & 0xffff0000u);
}

__device__ __forceinline__ void place(unsigned int u, int* c1,
                                      unsigned short* slots) {
  const int lv = (int)((u >> 16) & 127u);
  const int pos = atomicAdd(&c1[lv], 1);
  if (pos < VCAP) slots[lv * VCAP + pos] = (unsigned short)(u & 0xffffu);
}

__global__ __launch_bounds__(1024) void gather_kernel(
    const uint4* __restrict__ table4, const unsigned int* __restrict__ records,
    const int* __restrict__ gcur, const float4* __restrict__ xv4,
    float4* __restrict__ out4) {
  __shared__ int c1[128];
  __shared__ unsigned short slots[128 * VCAP];  // 16 KB
  const int t = threadIdx.x;  // 0..1023
  const int hb = blockIdx.x;
  const int start = hb * BCAP;
  const int nrec = gcur[hb];
  const int g = t >> 3;  // 0..127
  const int c = t & 7;
  const int v = hb * 128 + g;
  const size_t ob = (size_t)v * 16 + c * 2;

  // prefetch x_v early: independent of the scan, hides HBM/L3 latency
  float4 x0 = {0.f, 0.f, 0.f, 0.f}, x1 = x0;
  if (v < NN) {
    x0 = xv4[ob];
    x1 = xv4[ob + 1];
  }

  if (t < 128) c1[t] = 0;
  __syncthreads();

  const uint4* rec4 = (const uint4*)(records + start);
  const int nfull = nrec >> 2;
  for (int q = t; q < nfull; q += 1024) {
    const uint4 u = rec4[q];
    place(u.x, c1, slots);
    place(u.y, c1, slots);
    place(u.z, c1, slots);
    place(u.w, c1, slots);
  }
  for (int j = (nfull << 2) + t; j < nrec; j += 1024)
    place(records[start + j], c1, slots);
  __syncthreads();

  // pad each list to a multiple of 8 with the zeros row
  if (t < 128) {
    int n = c1[t];
    n = (n > VCAP) ? VCAP : n;
    const int np = (n + 7) & ~7;
    for (int i = n; i < np; ++i) slots[t * VCAP + i] = (unsigned short)ZROW;
    c1[t] = np;
  }
  __syncthreads();

  if (v >= NN) return;
  const int n = c1[g];  // multiple of 8, <= 64
  const unsigned short* sl = slots + g * VCAP;

  float a[8];
#pragma unroll
  for (int r = 0; r < 8; ++r) a[r] = 0.f;

  for (int i = 0; i < n; i += 8) {
    const int e0 = sl[i + 0];
    const int e1 = sl[i + 1];
    const int e2 = sl[i + 2];
    const int e3 = sl[i + 3];
    const int e4 = sl[i + 4];
    const int e5 = sl[i + 5];
    const int e6 = sl[i + 6];
    const int e7 = sl[i + 7];
    const uint4 t0 = table4[(size_t)e0 * 8 + c];
    const uint4 t1 = table4[(size_t)e1 * 8 + c];
    const uint4 t2 = table4[(size_t)e2 * 8 + c];
    const uint4 t3 = table4[(size_t)e3 * 8 + c];
    const uint4 t4 = table4[(size_t)e4 * 8 + c];
    const uint4 t5 = table4[(size_t)e5 * 8 + c];
    const uint4 t6 = table4[(size_t)e6 * 8 + c];
    const uint4 t7 = table4[(size_t)e7 * 8 + c];
    acc8(a, t0); acc8(a, t1); acc8(a, t2); acc8(a, t3);
    acc8(a, t4); acc8(a, t5); acc8(a, t6); acc8(a, t7);
  }

  float4 o0, o1;
  o0.x = fmaxf(x0.x + a[0], 0.f);
  o0.y = fmaxf(x0.y + a[1], 0.f);
  o0.z = fmaxf(x0.z + a[2], 0.f);
  o0.w = fmaxf(x0.w + a[3], 0.f);
  o1.x = fmaxf(x1.x + a[4], 0.f);
  o1.y = fmaxf(x1.y + a[5], 0.f);
  o1.z = fmaxf(x1.z + a[6], 0.f);
  o1.w = fmaxf(x1.w + a[7], 0.f);
  out4[ob] = o0;
  out4[ob + 1] = o1;
}

extern "C" void kernel_launch(void* const* d_in, const int* in_sizes, int n_in,
                              void* d_out, int out_size, void* d_ws,
                              size_t ws_size, hipStream_t stream) {
  const float* x_v = (const float*)d_in[0];
  const float* x_c = (const float*)d_in[1];
  const float* W1v = (const float*)d_in[2];
  const float* b1v = (const float*)d_in[3];
  const float* W2v = (const float*)d_in[4];
  const float* b2v = (const float*)d_in[5];
  const float* W1c = (const float*)d_in[6];
  const float* b1c = (const float*)d_in[7];
  const float* W2c = (const float*)d_in[8];
  const float* b2c = (const float*)d_in[9];
  const int* src_vv = (const int*)d_in[10];
  const int* dst_vv = (const int*)d_in[11];
  const int* src_vc = (const int*)d_in[12];
  const int* dst_vc = (const int*)d_in[13];
  float* out = (float*)d_out;

  // workspace: table(bf16, +1 zeros row) | records 6.40 MB | wt 64 KB | gcur
  char* p = (char*)d_ws;
  unsigned short* table = (unsigned short*)p;
  p += (size_t)(NN + NC + 1) * DD * sizeof(unsigned short);
  unsigned int* records = (unsigned int*)p;
  p += (size_t)NHB * BCAP * sizeof(unsigned int);
  unsigned short* wt = (unsigned short*)p;
  p += (size_t)4 * 8192 * sizeof(unsigned short);
  int* gcur = (int*)p;

  prep_kernel<<<128, 256, 0, stream>>>(W1v, W2v, W1c, W2c, wt, gcur, table);

  k1_kernel<<<K1_B, 1024, 0, stream>>>(x_v, x_c, b1v, b2v, b1c, b2c, wt,
                                       src_vv, dst_vv, src_vc, dst_vc, table,
                                       gcur, records);

  gather_kernel<<<GAT_B, 1024, 0, stream>>>((const uint4*)table, records, gcur,
                                            (const float4*)x_v, (float4*)out);
}